// Round 24
// baseline (229.688 us; speedup 1.0000x reference)
//
#include <hip/hip_runtime.h>

typedef unsigned long long u64;
typedef unsigned int u32;
typedef unsigned short u16;
typedef unsigned char u8;

#define N_ROWS 16384
#define DIM    512
#define K_CODES 8192

#define CHUNKS 64
#define CHUNK_CODES 128
#define BMR 128
#define KC 64                 // fp8 k-elems per tile
#define KTILES (DIM / KC)     // 8

typedef int   i32x4  __attribute__((ext_vector_type(4)));
typedef int   i32x8  __attribute__((ext_vector_type(8)));
typedef float f32x16 __attribute__((ext_vector_type(16)));

// sorted ascending 3-slot insert (r14-verified)
__device__ __forceinline__ void t3_insert(u64* a, u64 k) {
    u64 x = k;
    bool l0 = x < a[0]; u64 n0 = l0 ? x : a[0]; x = l0 ? a[0] : x;
    bool l1 = x < a[1]; u64 n1 = l1 ? x : a[1]; x = l1 ? a[1] : x;
    bool l2 = x < a[2]; u64 n2 = l2 ? x : a[2];
    a[0] = n0; a[1] = n1; a[2] = n2;
}

// descending float triple insert: n0=max(p,v0); n1=clamp-mid; n2=clamp-mid
__device__ __forceinline__ void f3_insert(float& v0, float& v1, float& v2, float p) {
    float n0 = fmaxf(p, v0);
    float n1 = fminf(fmaxf(p, v1), v0);
    float n2 = fminf(fmaxf(p, v2), v1);
    v0 = n0; v1 = n1; v2 = n2;
}

// ---------------- Kernel P: fp8 e4m3 split; cb pre-scaled by 2^13 (verified r22) ----
__global__ void vq_split_kernel(const float* __restrict__ x, const float* __restrict__ cb,
                                u32* __restrict__ xf8, u32* __restrict__ cf8) {
    size_t t = (size_t)blockIdx.x * blockDim.x + threadIdx.x;
    const size_t nx = (size_t)N_ROWS * DIM / 4;
    const size_t nc = (size_t)K_CODES * DIM / 4;
    if (t < nx) {
        float4 v = ((const float4*)x)[t];
        u32 r = (u32)__builtin_amdgcn_cvt_pk_fp8_f32(v.x, v.y, 0, false);
        r = (u32)__builtin_amdgcn_cvt_pk_fp8_f32(v.z, v.w, (int)r, true);
        xf8[t] = r;
    } else if (t < nx + nc) {
        float4 v = ((const float4*)cb)[t - nx];
        u32 r = (u32)__builtin_amdgcn_cvt_pk_fp8_f32(v.x * 8192.0f, v.y * 8192.0f, 0, false);
        r = (u32)__builtin_amdgcn_cvt_pk_fp8_f32(v.z * 8192.0f, v.w * 8192.0f, (int)r, true);
        cf8[t - nx] = r;
    }
}

// ---------------- Kernel N: numpy-pairwise fp32 row norms, wave-parallel (verified r18) ----
__global__ void vq_np_norm_kernel(const float* __restrict__ x, const float* __restrict__ cb,
                                  float* __restrict__ Arow, float* __restrict__ Bcode) {
    int wid = (blockIdx.x * blockDim.x + threadIdx.x) >> 6;
    int lane = threadIdx.x & 63;
    int r2 = lane >> 5;
    int b  = (lane >> 3) & 3;
    int j  = lane & 7;
    int row = wid * 2 + r2;
    const float* p;
    float* o;
    if (row < N_ROWS) { p = x + (size_t)row * DIM; o = Arow + row; }
    else              { int c = row - N_ROWS; p = cb + (size_t)c * DIM; o = Bcode + c; }
    const float* q = p + b * 128 + j;
    float v0 = q[0];
    float s = __fmul_rn(v0, v0);
    #pragma unroll
    for (int i = 1; i < 16; ++i) {
        float v = q[8 * i];
        s = __fadd_rn(s, __fmul_rn(v, v));
    }
    s = __fadd_rn(s, __shfl_xor(s, 1));
    s = __fadd_rn(s, __shfl_xor(s, 2));
    s = __fadd_rn(s, __shfl_xor(s, 4));
    s = __fadd_rn(s, __shfl_xor(s, 8));
    s = __fadd_rn(s, __shfl_xor(s, 16));
    if ((lane & 31) == 0) *o = s;
}

// ---------------- Kernel S: fp8 MFMA screen, slot-major LDS + packed-idx fold -------
// LDS plane layout [slot][row] (slot = 16B k-chunk 0..3): each b128 frag read is two
// contiguous 512B half-runs 2048B apart (2-way aliasing = free). Staging = 16 segs of
// (64 rows x 1 slot), linear dest, source row(lane)*512 + slot*16 — no swizzle.
// Fold packs idx into value's low 13 mantissa bits (granularity << fp8 noise);
// top-3 via float min/max network. Same MFMA bytes/lane as verified r22/r23.
__launch_bounds__(256, 3)
__global__ void vq_screen_kernel(const u8* __restrict__ xf8, const u8* __restrict__ cf8,
                                 u64* __restrict__ top3out) {
    __shared__ __align__(16) u8 lds[3][16384];   // X slots @0 (4x2048B) | C slots @8192

    const int t = threadIdx.x;
    const int lane = t & 63;
    const int w = t >> 6;        // 0..3
    const int wrow  = w >> 1;    // 0..1 -> x-rows [64*wrow, +64)
    const int wcode = w & 1;     // 0..1 -> codes  [64*wcode, +64)
    const int l31 = lane & 31;
    const int h = lane >> 5;     // k-half selector

    const int rowBase   = blockIdx.x * BMR;
    const int chunkBase = blockIdx.y * CHUNK_CODES;

    // 16 staging segs: q<8 = X (slot=q&3, rh=q>>2), q>=8 = C
    const u8* srcs[4];
    int dsts[4];
    #pragma unroll
    for (int j = 0; j < 4; ++j) {
        int q = j * 4 + w;
        int qq = q & 7;
        int slot = qq & 3, rh = qq >> 2;
        const u8* gp = (q < 8) ? (xf8 + (size_t)(rowBase + rh * 64 + lane) * DIM)
                               : (cf8 + (size_t)(chunkBase + rh * 64 + lane) * DIM);
        srcs[j] = gp + slot * 16;
        dsts[j] = (q < 8 ? 0 : 8192) + slot * 2048 + rh * 1024;
    }

    auto stage = [&](int kt) {
        u8* B = &lds[kt % 3][0];
        #pragma unroll
        for (int j = 0; j < 4; ++j) {
            __builtin_amdgcn_global_load_lds(
                (const __attribute__((address_space(1))) u32*)(srcs[j] + kt * KC),
                (__attribute__((address_space(3))) u32*)(B + dsts[j]),
                16, 0, 0);
        }
    };

    // fragment offsets (kt-invariant): slot = h*2 + b
    int aOff0[2], aOff1[2], bOff0[2], bOff1[2];
    #pragma unroll
    for (int mi = 0; mi < 2; ++mi) {
        int rc = wcode * 64 + mi * 32 + l31;
        aOff0[mi] = 8192 + (h * 2 + 0) * 2048 + rc * 16;
        aOff1[mi] = 8192 + (h * 2 + 1) * 2048 + rc * 16;
    }
    #pragma unroll
    for (int ni = 0; ni < 2; ++ni) {
        int rx = wrow * 64 + ni * 32 + l31;
        bOff0[ni] = (h * 2 + 0) * 2048 + rx * 16;
        bOff1[ni] = (h * 2 + 1) * 2048 + rx * 16;
    }

    f32x16 acc[2][2] = {};

    stage(0);
    stage(1);

    #pragma unroll
    for (int kt = 0; kt < KTILES; ++kt) {
        if (kt + 1 < KTILES) {
            asm volatile("s_waitcnt vmcnt(4)" ::: "memory");   // stage(kt) complete
        } else {
            asm volatile("s_waitcnt vmcnt(0)" ::: "memory");
        }
        asm volatile("s_barrier" ::: "memory");
        if (kt + 2 < KTILES) stage(kt + 2);

        const u8* L = &lds[kt % 3][0];
        i32x8 Af[2], Bf[2];
        #pragma unroll
        for (int mi = 0; mi < 2; ++mi) {
            *(i32x4*)&Af[mi]       = *(const i32x4*)(L + aOff0[mi]);
            *((i32x4*)&Af[mi] + 1) = *(const i32x4*)(L + aOff1[mi]);
        }
        #pragma unroll
        for (int ni = 0; ni < 2; ++ni) {
            *(i32x4*)&Bf[ni]       = *(const i32x4*)(L + bOff0[ni]);
            *((i32x4*)&Bf[ni] + 1) = *(const i32x4*)(L + bOff1[ni]);
        }
        __builtin_amdgcn_s_setprio(1);
        #pragma unroll
        for (int ni = 0; ni < 2; ++ni)
            #pragma unroll
            for (int mi = 0; mi < 2; ++mi)
                acc[mi][ni] = __builtin_amdgcn_mfma_scale_f32_32x32x64_f8f6f4(
                    Af[mi], Bf[ni], acc[mi][ni], 0, 0, 0, 127, 0, 127);
        __builtin_amdgcn_s_setprio(0);
    }

    // ---- fold: pack idx into low 13 mantissa bits; float top-3; 1 shfl merge ----
    __syncthreads();
    u64* t3buf = (u64*)&lds[0][0];   // [128 rows][2 wcode][3 slots] = 6KB

    #pragma unroll
    for (int ni = 0; ni < 2; ++ni) {
        float p0 = -3.4e38f, p1 = -3.4e38f, p2 = -3.4e38f;
        #pragma unroll
        for (int mi = 0; mi < 2; ++mi) {
            const u32 cb0u = (u32)(chunkBase + wcode * 64 + mi * 32 + 4 * h);
            #pragma unroll
            for (int reg = 0; reg < 16; ++reg) {
                u32 pr = (__float_as_uint(acc[mi][ni][reg]) & 0xFFFFE000u)
                       | cb0u | (u32)((reg & 3) + 8 * (reg >> 2));
                f3_insert(p0, p1, p2, __uint_as_float(pr));
            }
        }
        // merge with lane^32 (same xrow, complementary codes)
        float q0 = __shfl_xor(p0, 32), q1 = __shfl_xor(p1, 32), q2 = __shfl_xor(p2, 32);
        f3_insert(p0, p1, p2, q0);
        f3_insert(p0, p1, p2, q1);
        f3_insert(p0, p1, p2, q2);
        if (h == 0) {
            int xrl = wrow * 64 + ni * 32 + l31;
            u32 s0 = __float_as_uint(p0);
            u32 k0 = (p0 < 0.0f) ? s0 : (~s0 & 0x7FFFFFFFu);
            u32 s1 = __float_as_uint(p1);
            u32 k1 = (p1 < 0.0f) ? s1 : (~s1 & 0x7FFFFFFFu);
            u32 s2 = __float_as_uint(p2);
            u32 k2 = (p2 < 0.0f) ? s2 : (~s2 & 0x7FFFFFFFu);
            t3buf[(xrl * 2 + wcode) * 3 + 0] = ((u64)k0 << 13) | (u64)(s0 & 8191u);
            t3buf[(xrl * 2 + wcode) * 3 + 1] = ((u64)k1 << 13) | (u64)(s1 & 8191u);
            t3buf[(xrl * 2 + wcode) * 3 + 2] = ((u64)k2 << 13) | (u64)(s2 & 8191u);
        }
    }
    __syncthreads();
    if (t < BMR) {
        u64 best[3];
        best[0] = t3buf[(t * 2 + 0) * 3 + 0];
        best[1] = t3buf[(t * 2 + 0) * 3 + 1];
        best[2] = t3buf[(t * 2 + 0) * 3 + 2];
        t3_insert(best, t3buf[(t * 2 + 1) * 3 + 0]);
        t3_insert(best, t3buf[(t * 2 + 1) * 3 + 1]);
        t3_insert(best, t3buf[(t * 2 + 1) * 3 + 2]);
        size_t o = ((size_t)blockIdx.y * N_ROWS + rowBase + t) * 3;
        top3out[o + 0] = best[0];
        top3out[o + 1] = best[1];
        top3out[o + 2] = best[2];
    }
}

// ---------------- Kernel R: global top-8 of 64x3 keys -> exact np re-decision (r14) ---
__global__ void vq_refine_kernel(const float* __restrict__ x, const float* __restrict__ cb,
                                 const float* __restrict__ Arow, const float* __restrict__ Bcode,
                                 const u64* __restrict__ top3, int* __restrict__ idxOut,
                                 float* __restrict__ out4) {
    int gw = (blockIdx.x * blockDim.x + threadIdx.x) >> 6;
    int lane = threadIdx.x & 63;
    if (gw >= N_ROWS) return;

    const u64* tp = top3 + ((size_t)lane * N_ROWS + gw) * 3;
    u64 a0 = tp[0], a1 = tp[1], a2 = tp[2];

    u64 cand[8];
    #pragma unroll
    for (int j = 0; j < 8; ++j) {
        u64 m = a0;
        #pragma unroll
        for (int s = 1; s < 64; s <<= 1) { u64 o = __shfl_xor(m, s); m = o < m ? o : m; }
        cand[j] = m;
        if (a0 == m) { a0 = a1; a1 = a2; a2 = ~0ull; }
    }

    float Ai = Arow[gw];
    const float* xr = x + (size_t)gw * DIM;
    float xv[8];
    #pragma unroll
    for (int e = 0; e < 8; ++e) xv[e] = xr[e * 64 + lane];

    u64 best = ~0ull;
    #pragma unroll
    for (int j = 0; j < 8; ++j) {
        int c = (int)(cand[j] & 8191u);
        const float* er = cb + (size_t)c * DIM;
        double d = 0.0;
        #pragma unroll
        for (int e = 0; e < 8; ++e)
            d = fma((double)xv[e], (double)er[e * 64 + lane], d);
        #pragma unroll
        for (int m = 1; m < 64; m <<= 1) d += __shfl_xor(d, m);
        float m32 = (float)d;
        float dist = __fsub_rn(__fadd_rn(Ai, Bcode[c]), 2.0f * m32);
        u64 ek = ((u64)__float_as_uint(dist) << 13) | (u64)(u32)c;
        best = ek < best ? ek : best;
    }
    if (lane == 0) {
        int c = (int)(best & 8191u);
        idxOut[gw] = c;
        out4[gw] = (float)c;
    }
}

// ---------------- Kernel C: gather + outputs + per-row loss partial ----------------
__global__ void vq_gather_kernel(const float* __restrict__ x,
                                 const float* __restrict__ cb,
                                 const int* __restrict__ idxArr,
                                 float* __restrict__ out0,
                                 float* __restrict__ out3,
                                 float* __restrict__ rowPart) {
    int gw = (blockIdx.x * blockDim.x + threadIdx.x) >> 6;
    int lane = threadIdx.x & 63;
    if (gw >= N_ROWS) return;
    int idx = idxArr[gw];
    const float2* xp = (const float2*)(x  + (size_t)gw * DIM);
    const float2* qp = (const float2*)(cb + (size_t)idx * DIM);
    float2* o0 = (float2*)(out0 + (size_t)gw * DIM);
    float2* o3 = (float2*)(out3 + (size_t)gw * DIM);
    float part = 0.0f;
    #pragma unroll
    for (int r = 0; r < 4; ++r) {
        int e = r * 64 + lane;
        float2 xv = xp[e];
        float2 qv = qp[e];
        float dx = qv.x - xv.x, dy = qv.y - xv.y;
        part += dx * dx + dy * dy;
        float2 o; o.x = xv.x + dx; o.y = xv.y + dy;
        o0[e] = o;
        o3[e] = qv;
    }
    #pragma unroll
    for (int m = 32; m; m >>= 1) part += __shfl_xor(part, m);
    if (lane == 0) rowPart[gw] = part;
}

// ---------------- Kernel D: deterministic loss reduce ----------------
__global__ void vq_loss_kernel(const float* __restrict__ rowPart,
                               float* __restrict__ out1, float* __restrict__ out2) {
    __shared__ float red[256];
    int t = threadIdx.x;
    float s = 0.0f;
    for (int r = t; r < N_ROWS; r += 256) s += rowPart[r];
    red[t] = s;
    __syncthreads();
    #pragma unroll
    for (int m = 128; m; m >>= 1) {
        if (t < m) red[t] += red[t + m];
        __syncthreads();
    }
    if (t == 0) {
        float loss = red[0] / (float)(N_ROWS * DIM);
        out1[0] = loss;
        out2[0] = loss;
    }
}

extern "C" void kernel_launch(void* const* d_in, const int* in_sizes, int n_in,
                              void* d_out, int out_size, void* d_ws, size_t ws_size,
                              hipStream_t stream) {
    const float* x  = (const float*)d_in[0];   // [16384, 512]
    const float* cb = (const float*)d_in[1];   // [8192, 512]
    float* out  = (float*)d_out;
    float* out0 = out;                         // quantized_out [8388608]
    float* out1 = out + 8388608;               // q_latent_loss [1]
    float* out2 = out + 8388609;               // e_latent_loss [1]
    float* out3 = out + 8388610;               // quantized [8388608]
    float* out4 = out + 16777218;              // idx as float [16384]

    // d_out scratch (stream-ordered; consumed before gather overwrites):
    // xf8 8.4MB + cf8 4.2MB in out0 region; top3 (64*16384*3 u64 = 25MB) in out3 region.
    u32* xf8   = (u32*)out0;                   // [0, 2097152) floats
    u32* cf8   = (u32*)(out + 2097152);        // [2097152, 3145728)
    u64* wsTop3 = (u64*)(out + 8388612);       // [8388612, 14680068)  8B-aligned

    char* ws = (char*)d_ws;
    float* wsA    = (float*)ws;                // 16384 f
    float* wsB    = (float*)(ws + 65536);      // 8192 f
    int*   wsIdx  = (int*)(ws + 98304);        // 16384 int
    float* wsPart = (float*)(ws + 163840);     // 16384 f

    hipLaunchKernelGGL(vq_split_kernel,   dim3(12288), dim3(256), 0, stream,
                       x, cb, xf8, cf8);
    hipLaunchKernelGGL(vq_np_norm_kernel, dim3(3072), dim3(256), 0, stream, x, cb, wsA, wsB);
    hipLaunchKernelGGL(vq_screen_kernel,  dim3(N_ROWS / BMR, CHUNKS), dim3(256), 0, stream,
                       (const u8*)xf8, (const u8*)cf8, wsTop3);
    hipLaunchKernelGGL(vq_refine_kernel,  dim3(4096), dim3(256), 0, stream,
                       x, cb, wsA, wsB, wsTop3, wsIdx, out4);
    hipLaunchKernelGGL(vq_gather_kernel,  dim3(4096), dim3(256), 0, stream,
                       x, cb, wsIdx, out0, out3, wsPart);
    hipLaunchKernelGGL(vq_loss_kernel,    dim3(1),    dim3(256), 0, stream,
                       wsPart, out1, out2);
}

// Round 25
// 198.387 us; speedup vs baseline: 1.1578x; 1.1578x over previous
//
#include <hip/hip_runtime.h>

typedef unsigned long long u64;
typedef unsigned int u32;
typedef unsigned short u16;
typedef unsigned char u8;

#define N_ROWS 16384
#define DIM    512
#define K_CODES 8192

#define CHUNKS 64
#define CHUNK_CODES 128
#define BMR 128
#define KC 64                 // fp8 k-elems per tile
#define KTILES (DIM / KC)     // 8

typedef int   i32x4  __attribute__((ext_vector_type(4)));
typedef int   i32x8  __attribute__((ext_vector_type(8)));
typedef float f32x16 __attribute__((ext_vector_type(16)));

// sorted ascending 3-slot insert (r14-verified)
__device__ __forceinline__ void t3_insert(u64* a, u64 k) {
    u64 x = k;
    bool l0 = x < a[0]; u64 n0 = l0 ? x : a[0]; x = l0 ? a[0] : x;
    bool l1 = x < a[1]; u64 n1 = l1 ? x : a[1]; x = l1 ? a[1] : x;
    bool l2 = x < a[2]; u64 n2 = l2 ? x : a[2];
    a[0] = n0; a[1] = n1; a[2] = n2;
}

// descending float triple insert (r24-verified)
__device__ __forceinline__ void f3_insert(float& v0, float& v1, float& v2, float p) {
    float n0 = fmaxf(p, v0);
    float n1 = fminf(fmaxf(p, v1), v0);
    float n2 = fminf(fmaxf(p, v2), v1);
    v0 = n0; v1 = n1; v2 = n2;
}

// ---------------- Kernel P: fp8 e4m3 split; cb pre-scaled by 2^13 (verified r22) ----
__global__ void vq_split_kernel(const float* __restrict__ x, const float* __restrict__ cb,
                                u32* __restrict__ xf8, u32* __restrict__ cf8) {
    size_t t = (size_t)blockIdx.x * blockDim.x + threadIdx.x;
    const size_t nx = (size_t)N_ROWS * DIM / 4;
    const size_t nc = (size_t)K_CODES * DIM / 4;
    if (t < nx) {
        float4 v = ((const float4*)x)[t];
        u32 r = (u32)__builtin_amdgcn_cvt_pk_fp8_f32(v.x, v.y, 0, false);
        r = (u32)__builtin_amdgcn_cvt_pk_fp8_f32(v.z, v.w, (int)r, true);
        xf8[t] = r;
    } else if (t < nx + nc) {
        float4 v = ((const float4*)cb)[t - nx];
        u32 r = (u32)__builtin_amdgcn_cvt_pk_fp8_f32(v.x * 8192.0f, v.y * 8192.0f, 0, false);
        r = (u32)__builtin_amdgcn_cvt_pk_fp8_f32(v.z * 8192.0f, v.w * 8192.0f, (int)r, true);
        cf8[t - nx] = r;
    }
}

// ---------------- Kernel N: numpy-pairwise fp32 row norms, wave-parallel (verified r18) ----
__global__ void vq_np_norm_kernel(const float* __restrict__ x, const float* __restrict__ cb,
                                  float* __restrict__ Arow, float* __restrict__ Bcode) {
    int wid = (blockIdx.x * blockDim.x + threadIdx.x) >> 6;
    int lane = threadIdx.x & 63;
    int r2 = lane >> 5;
    int b  = (lane >> 3) & 3;
    int j  = lane & 7;
    int row = wid * 2 + r2;
    const float* p;
    float* o;
    if (row < N_ROWS) { p = x + (size_t)row * DIM; o = Arow + row; }
    else              { int c = row - N_ROWS; p = cb + (size_t)c * DIM; o = Bcode + c; }
    const float* q = p + b * 128 + j;
    float v0 = q[0];
    float s = __fmul_rn(v0, v0);
    #pragma unroll
    for (int i = 1; i < 16; ++i) {
        float v = q[8 * i];
        s = __fadd_rn(s, __fmul_rn(v, v));
    }
    s = __fadd_rn(s, __shfl_xor(s, 1));
    s = __fadd_rn(s, __shfl_xor(s, 2));
    s = __fadd_rn(s, __shfl_xor(s, 4));
    s = __fadd_rn(s, __shfl_xor(s, 8));
    s = __fadd_rn(s, __shfl_xor(s, 16));
    if ((lane & 31) == 0) *o = s;
}

// ---------------- Kernel S: fp8 MFMA screen = r23 staging + r24 packed-idx fold -----
// Staging/LDS layout/frag offsets byte-identical to r23 (coalesced 64B global
// segments; slot swizzle (h*2+b)^((row>>1)&3)); fold = r24's f3_insert with idx
// packed into the value's low 13 mantissa bits (both halves verified absmax 0).
__launch_bounds__(256, 3)
__global__ void vq_screen_kernel(const u8* __restrict__ xf8, const u8* __restrict__ cf8,
                                 u64* __restrict__ top3out) {
    __shared__ __align__(16) u8 lds[3][16384];   // X[128][64] @0 | C[128][64] @8192

    const int t = threadIdx.x;
    const int lane = t & 63;
    const int w = t >> 6;        // 0..3
    const int wrow  = w >> 1;    // 0..1 -> x-rows [64*wrow, +64)
    const int wcode = w & 1;     // 0..1 -> codes  [64*wcode, +64)
    const int l31 = lane & 31;
    const int h = lane >> 5;     // k-half selector

    const int rowBase   = blockIdx.x * BMR;
    const int chunkBase = blockIdx.y * CHUNK_CODES;

    // staging: 16 segs of 1KB (16 rows x 64B); pre-swizzled source chunk (r23)
    const size_t laneOff = (size_t)(lane >> 2) * DIM
                         + (size_t)(((lane & 3) ^ ((lane >> 3) & 3)) * 16);
    const u8* srcs[4];
    int dsts[4];
    #pragma unroll
    for (int j = 0; j < 4; ++j) {
        int q = j * 4 + w;
        const u8* gp = (q < 8) ? (xf8 + (size_t)(rowBase + q * 16) * DIM)
                               : (cf8 + (size_t)(chunkBase + (q - 8) * 16) * DIM);
        srcs[j] = gp + laneOff;
        dsts[j] = q * 1024;
    }

    auto stage = [&](int kt) {
        u8* B = &lds[kt % 3][0];
        #pragma unroll
        for (int j = 0; j < 4; ++j) {
            __builtin_amdgcn_global_load_lds(
                (const __attribute__((address_space(1))) u32*)(srcs[j] + kt * KC),
                (__attribute__((address_space(3))) u32*)(B + dsts[j]),
                16, 0, 0);
        }
    };

    // fragment LDS byte offsets (kt-invariant); slot = (h*2+b) ^ ((row>>1)&3)  (r23)
    const int swz = (l31 >> 1) & 3;
    const int s0 = ((h * 2 + 0) ^ swz) * 16;
    const int s1 = ((h * 2 + 1) ^ swz) * 16;
    int aOff0[2], aOff1[2], bOff0[2], bOff1[2];
    #pragma unroll
    for (int mi = 0; mi < 2; ++mi) {
        int rc = wcode * 64 + mi * 32 + l31;
        aOff0[mi] = 8192 + rc * 64 + s0;
        aOff1[mi] = 8192 + rc * 64 + s1;
    }
    #pragma unroll
    for (int ni = 0; ni < 2; ++ni) {
        int rx = wrow * 64 + ni * 32 + l31;
        bOff0[ni] = rx * 64 + s0;
        bOff1[ni] = rx * 64 + s1;
    }

    f32x16 acc[2][2] = {};

    stage(0);
    stage(1);

    #pragma unroll
    for (int kt = 0; kt < KTILES; ++kt) {
        if (kt + 1 < KTILES) {
            asm volatile("s_waitcnt vmcnt(4)" ::: "memory");   // stage(kt) complete
        } else {
            asm volatile("s_waitcnt vmcnt(0)" ::: "memory");
        }
        asm volatile("s_barrier" ::: "memory");
        if (kt + 2 < KTILES) stage(kt + 2);

        const u8* L = &lds[kt % 3][0];
        i32x8 Af[2], Bf[2];
        #pragma unroll
        for (int mi = 0; mi < 2; ++mi) {
            *(i32x4*)&Af[mi]       = *(const i32x4*)(L + aOff0[mi]);
            *((i32x4*)&Af[mi] + 1) = *(const i32x4*)(L + aOff1[mi]);
        }
        #pragma unroll
        for (int ni = 0; ni < 2; ++ni) {
            *(i32x4*)&Bf[ni]       = *(const i32x4*)(L + bOff0[ni]);
            *((i32x4*)&Bf[ni] + 1) = *(const i32x4*)(L + bOff1[ni]);
        }
        __builtin_amdgcn_s_setprio(1);
        #pragma unroll
        for (int ni = 0; ni < 2; ++ni)
            #pragma unroll
            for (int mi = 0; mi < 2; ++mi)
                acc[mi][ni] = __builtin_amdgcn_mfma_scale_f32_32x32x64_f8f6f4(
                    Af[mi], Bf[ni], acc[mi][ni], 0, 0, 0, 127, 0, 127);
        __builtin_amdgcn_s_setprio(0);
    }

    // ---- fold (r24): pack idx into low 13 mantissa bits; float top-3; 1 shfl merge ----
    __syncthreads();
    u64* t3buf = (u64*)&lds[0][0];   // [128 rows][2 wcode][3 slots] = 6KB

    #pragma unroll
    for (int ni = 0; ni < 2; ++ni) {
        float p0 = -3.4e38f, p1 = -3.4e38f, p2 = -3.4e38f;
        #pragma unroll
        for (int mi = 0; mi < 2; ++mi) {
            const u32 cb0u = (u32)(chunkBase + wcode * 64 + mi * 32 + 4 * h);
            #pragma unroll
            for (int reg = 0; reg < 16; ++reg) {
                u32 pr = (__float_as_uint(acc[mi][ni][reg]) & 0xFFFFE000u)
                       | cb0u | (u32)((reg & 3) + 8 * (reg >> 2));
                f3_insert(p0, p1, p2, __uint_as_float(pr));
            }
        }
        // merge with lane^32 (same xrow, complementary codes)
        float q0 = __shfl_xor(p0, 32), q1 = __shfl_xor(p1, 32), q2 = __shfl_xor(p2, 32);
        f3_insert(p0, p1, p2, q0);
        f3_insert(p0, p1, p2, q1);
        f3_insert(p0, p1, p2, q2);
        if (h == 0) {
            int xrl = wrow * 64 + ni * 32 + l31;
            u32 s0b = __float_as_uint(p0);
            u32 k0 = (p0 < 0.0f) ? s0b : (~s0b & 0x7FFFFFFFu);
            u32 s1b = __float_as_uint(p1);
            u32 k1 = (p1 < 0.0f) ? s1b : (~s1b & 0x7FFFFFFFu);
            u32 s2b = __float_as_uint(p2);
            u32 k2 = (p2 < 0.0f) ? s2b : (~s2b & 0x7FFFFFFFu);
            t3buf[(xrl * 2 + wcode) * 3 + 0] = ((u64)k0 << 13) | (u64)(s0b & 8191u);
            t3buf[(xrl * 2 + wcode) * 3 + 1] = ((u64)k1 << 13) | (u64)(s1b & 8191u);
            t3buf[(xrl * 2 + wcode) * 3 + 2] = ((u64)k2 << 13) | (u64)(s2b & 8191u);
        }
    }
    __syncthreads();
    if (t < BMR) {
        u64 best[3];
        best[0] = t3buf[(t * 2 + 0) * 3 + 0];
        best[1] = t3buf[(t * 2 + 0) * 3 + 1];
        best[2] = t3buf[(t * 2 + 0) * 3 + 2];
        t3_insert(best, t3buf[(t * 2 + 1) * 3 + 0]);
        t3_insert(best, t3buf[(t * 2 + 1) * 3 + 1]);
        t3_insert(best, t3buf[(t * 2 + 1) * 3 + 2]);
        size_t o = ((size_t)blockIdx.y * N_ROWS + rowBase + t) * 3;
        top3out[o + 0] = best[0];
        top3out[o + 1] = best[1];
        top3out[o + 2] = best[2];
    }
}

// ---------------- Kernel R: global top-8 of 64x3 keys -> exact np re-decision (r14) ---
__global__ void vq_refine_kernel(const float* __restrict__ x, const float* __restrict__ cb,
                                 const float* __restrict__ Arow, const float* __restrict__ Bcode,
                                 const u64* __restrict__ top3, int* __restrict__ idxOut,
                                 float* __restrict__ out4) {
    int gw = (blockIdx.x * blockDim.x + threadIdx.x) >> 6;
    int lane = threadIdx.x & 63;
    if (gw >= N_ROWS) return;

    const u64* tp = top3 + ((size_t)lane * N_ROWS + gw) * 3;
    u64 a0 = tp[0], a1 = tp[1], a2 = tp[2];

    u64 cand[8];
    #pragma unroll
    for (int j = 0; j < 8; ++j) {
        u64 m = a0;
        #pragma unroll
        for (int s = 1; s < 64; s <<= 1) { u64 o = __shfl_xor(m, s); m = o < m ? o : m; }
        cand[j] = m;
        if (a0 == m) { a0 = a1; a1 = a2; a2 = ~0ull; }
    }

    float Ai = Arow[gw];
    const float* xr = x + (size_t)gw * DIM;
    float xv[8];
    #pragma unroll
    for (int e = 0; e < 8; ++e) xv[e] = xr[e * 64 + lane];

    u64 best = ~0ull;
    #pragma unroll
    for (int j = 0; j < 8; ++j) {
        int c = (int)(cand[j] & 8191u);
        const float* er = cb + (size_t)c * DIM;
        double d = 0.0;
        #pragma unroll
        for (int e = 0; e < 8; ++e)
            d = fma((double)xv[e], (double)er[e * 64 + lane], d);
        #pragma unroll
        for (int m = 1; m < 64; m <<= 1) d += __shfl_xor(d, m);
        float m32 = (float)d;
        float dist = __fsub_rn(__fadd_rn(Ai, Bcode[c]), 2.0f * m32);
        u64 ek = ((u64)__float_as_uint(dist) << 13) | (u64)(u32)c;
        best = ek < best ? ek : best;
    }
    if (lane == 0) {
        int c = (int)(best & 8191u);
        idxOut[gw] = c;
        out4[gw] = (float)c;
    }
}

// ---------------- Kernel C: gather + outputs + per-row loss partial ----------------
__global__ void vq_gather_kernel(const float* __restrict__ x,
                                 const float* __restrict__ cb,
                                 const int* __restrict__ idxArr,
                                 float* __restrict__ out0,
                                 float* __restrict__ out3,
                                 float* __restrict__ rowPart) {
    int gw = (blockIdx.x * blockDim.x + threadIdx.x) >> 6;
    int lane = threadIdx.x & 63;
    if (gw >= N_ROWS) return;
    int idx = idxArr[gw];
    const float2* xp = (const float2*)(x  + (size_t)gw * DIM);
    const float2* qp = (const float2*)(cb + (size_t)idx * DIM);
    float2* o0 = (float2*)(out0 + (size_t)gw * DIM);
    float2* o3 = (float2*)(out3 + (size_t)gw * DIM);
    float part = 0.0f;
    #pragma unroll
    for (int r = 0; r < 4; ++r) {
        int e = r * 64 + lane;
        float2 xv = xp[e];
        float2 qv = qp[e];
        float dx = qv.x - xv.x, dy = qv.y - xv.y;
        part += dx * dx + dy * dy;
        float2 o; o.x = xv.x + dx; o.y = xv.y + dy;
        o0[e] = o;
        o3[e] = qv;
    }
    #pragma unroll
    for (int m = 32; m; m >>= 1) part += __shfl_xor(part, m);
    if (lane == 0) rowPart[gw] = part;
}

// ---------------- Kernel D: deterministic loss reduce ----------------
__global__ void vq_loss_kernel(const float* __restrict__ rowPart,
                               float* __restrict__ out1, float* __restrict__ out2) {
    __shared__ float red[256];
    int t = threadIdx.x;
    float s = 0.0f;
    for (int r = t; r < N_ROWS; r += 256) s += rowPart[r];
    red[t] = s;
    __syncthreads();
    #pragma unroll
    for (int m = 128; m; m >>= 1) {
        if (t < m) red[t] += red[t + m];
        __syncthreads();
    }
    if (t == 0) {
        float loss = red[0] / (float)(N_ROWS * DIM);
        out1[0] = loss;
        out2[0] = loss;
    }
}

extern "C" void kernel_launch(void* const* d_in, const int* in_sizes, int n_in,
                              void* d_out, int out_size, void* d_ws, size_t ws_size,
                              hipStream_t stream) {
    const float* x  = (const float*)d_in[0];   // [16384, 512]
    const float* cb = (const float*)d_in[1];   // [8192, 512]
    float* out  = (float*)d_out;
    float* out0 = out;                         // quantized_out [8388608]
    float* out1 = out + 8388608;               // q_latent_loss [1]
    float* out2 = out + 8388609;               // e_latent_loss [1]
    float* out3 = out + 8388610;               // quantized [8388608]
    float* out4 = out + 16777218;              // idx as float [16384]

    // d_out scratch (stream-ordered; consumed before gather overwrites):
    // xf8 8.4MB + cf8 4.2MB in out0 region; top3 (64*16384*3 u64 = 25MB) in out3 region.
    u32* xf8   = (u32*)out0;                   // [0, 2097152) floats
    u32* cf8   = (u32*)(out + 2097152);        // [2097152, 3145728)
    u64* wsTop3 = (u64*)(out + 8388612);       // [8388612, 14680068)  8B-aligned

    char* ws = (char*)d_ws;
    float* wsA    = (float*)ws;                // 16384 f
    float* wsB    = (float*)(ws + 65536);      // 8192 f
    int*   wsIdx  = (int*)(ws + 98304);        // 16384 int
    float* wsPart = (float*)(ws + 163840);     // 16384 f

    hipLaunchKernelGGL(vq_split_kernel,   dim3(12288), dim3(256), 0, stream,
                       x, cb, xf8, cf8);
    hipLaunchKernelGGL(vq_np_norm_kernel, dim3(3072), dim3(256), 0, stream, x, cb, wsA, wsB);
    hipLaunchKernelGGL(vq_screen_kernel,  dim3(N_ROWS / BMR, CHUNKS), dim3(256), 0, stream,
                       (const u8*)xf8, (const u8*)cf8, wsTop3);
    hipLaunchKernelGGL(vq_refine_kernel,  dim3(4096), dim3(256), 0, stream,
                       x, cb, wsA, wsB, wsTop3, wsIdx, out4);
    hipLaunchKernelGGL(vq_gather_kernel,  dim3(4096), dim3(256), 0, stream,
                       x, cb, wsIdx, out0, out3, wsPart);
    hipLaunchKernelGGL(vq_loss_kernel,    dim3(1),    dim3(256), 0, stream,
                       wsPart, out1, out2);
}

// Round 26
// 190.687 us; speedup vs baseline: 1.2045x; 1.0404x over previous
//
#include <hip/hip_runtime.h>

typedef unsigned long long u64;
typedef unsigned int u32;
typedef unsigned short u16;
typedef unsigned char u8;

#define N_ROWS 16384
#define DIM    512
#define K_CODES 8192

#define CHUNKS 64
#define CHUNK_CODES 128
#define BMR 128
#define KC 64                 // fp8 k-elems per tile
#define KTILES (DIM / KC)     // 8

typedef int   i32x4  __attribute__((ext_vector_type(4)));
typedef int   i32x8  __attribute__((ext_vector_type(8)));
typedef float f32x16 __attribute__((ext_vector_type(16)));

// sorted ascending 3-slot insert (r14-verified)
__device__ __forceinline__ void t3_insert(u64* a, u64 k) {
    u64 x = k;
    bool l0 = x < a[0]; u64 n0 = l0 ? x : a[0]; x = l0 ? a[0] : x;
    bool l1 = x < a[1]; u64 n1 = l1 ? x : a[1]; x = l1 ? a[1] : x;
    bool l2 = x < a[2]; u64 n2 = l2 ? x : a[2];
    a[0] = n0; a[1] = n1; a[2] = n2;
}

// descending float triple insert (r24-verified)
__device__ __forceinline__ void f3_insert(float& v0, float& v1, float& v2, float p) {
    float n0 = fmaxf(p, v0);
    float n1 = fminf(fmaxf(p, v1), v0);
    float n2 = fminf(fmaxf(p, v2), v1);
    v0 = n0; v1 = n1; v2 = n2;
}

// ---------------- Kernel PN: fused fp8 split + numpy-pairwise norms -----------------
// One wave per 2 rows. Split: 4 consecutive float4 per lane, uint4-coalesced fp8
// store (formulas identical to r22-verified split; x scale 1.0 exact, cb x2^13 exact).
// Norm: r18-verified exact-np lane mapping, rows L1/L2-hot from the split phase.
__global__ void vq_prep_kernel(const float* __restrict__ x, const float* __restrict__ cb,
                               u32* __restrict__ xf8, u32* __restrict__ cf8,
                               float* __restrict__ Arow, float* __restrict__ Bcode) {
    int wid = (blockIdx.x * blockDim.x + threadIdx.x) >> 6;
    int lane = threadIdx.x & 63;
    int r2 = lane >> 5;
    int row = wid * 2 + r2;
    bool isX = row < N_ROWS;
    const float* p = isX ? (x + (size_t)row * DIM)
                         : (cb + (size_t)(row - N_ROWS) * DIM);

    // ---- split phase ----
    {
        int g4 = (lane & 31) * 4;                 // float4 index base within row
        const float4* pv = (const float4*)p;
        float scale = isX ? 1.0f : 8192.0f;
        u32 r4[4];
        #pragma unroll
        for (int i = 0; i < 4; ++i) {
            float4 v = pv[g4 + i];
            u32 r = (u32)__builtin_amdgcn_cvt_pk_fp8_f32(v.x * scale, v.y * scale, 0, false);
            r = (u32)__builtin_amdgcn_cvt_pk_fp8_f32(v.z * scale, v.w * scale, (int)r, true);
            r4[i] = r;
        }
        u32* dst = isX ? (xf8 + (size_t)row * 128)
                       : (cf8 + (size_t)(row - N_ROWS) * 128);
        *(uint4*)(dst + g4) = make_uint4(r4[0], r4[1], r4[2], r4[3]);
    }

    // ---- norm phase (exact np pairwise; verified r18) ----
    int b = (lane >> 3) & 3;
    int j = lane & 7;
    const float* q = p + b * 128 + j;
    float v0 = q[0];
    float s = __fmul_rn(v0, v0);
    #pragma unroll
    for (int i = 1; i < 16; ++i) {
        float v = q[8 * i];
        s = __fadd_rn(s, __fmul_rn(v, v));
    }
    s = __fadd_rn(s, __shfl_xor(s, 1));
    s = __fadd_rn(s, __shfl_xor(s, 2));
    s = __fadd_rn(s, __shfl_xor(s, 4));
    s = __fadd_rn(s, __shfl_xor(s, 8));
    s = __fadd_rn(s, __shfl_xor(s, 16));
    if ((lane & 31) == 0) {
        float* o = isX ? (Arow + row) : (Bcode + (row - N_ROWS));
        *o = s;
    }
}

// ---------------- Kernel S: fp8 MFMA screen (verified r25) -------------------------
__launch_bounds__(256, 3)
__global__ void vq_screen_kernel(const u8* __restrict__ xf8, const u8* __restrict__ cf8,
                                 u64* __restrict__ top3out) {
    __shared__ __align__(16) u8 lds[3][16384];   // X[128][64] @0 | C[128][64] @8192

    const int t = threadIdx.x;
    const int lane = t & 63;
    const int w = t >> 6;        // 0..3
    const int wrow  = w >> 1;    // 0..1 -> x-rows [64*wrow, +64)
    const int wcode = w & 1;     // 0..1 -> codes  [64*wcode, +64)
    const int l31 = lane & 31;
    const int h = lane >> 5;     // k-half selector

    const int rowBase   = blockIdx.x * BMR;
    const int chunkBase = blockIdx.y * CHUNK_CODES;

    // staging: 16 segs of 1KB (16 rows x 64B); pre-swizzled source chunk
    const size_t laneOff = (size_t)(lane >> 2) * DIM
                         + (size_t)(((lane & 3) ^ ((lane >> 3) & 3)) * 16);
    const u8* srcs[4];
    int dsts[4];
    #pragma unroll
    for (int j = 0; j < 4; ++j) {
        int q = j * 4 + w;
        const u8* gp = (q < 8) ? (xf8 + (size_t)(rowBase + q * 16) * DIM)
                               : (cf8 + (size_t)(chunkBase + (q - 8) * 16) * DIM);
        srcs[j] = gp + laneOff;
        dsts[j] = q * 1024;
    }

    auto stage = [&](int kt) {
        u8* B = &lds[kt % 3][0];
        #pragma unroll
        for (int j = 0; j < 4; ++j) {
            __builtin_amdgcn_global_load_lds(
                (const __attribute__((address_space(1))) u32*)(srcs[j] + kt * KC),
                (__attribute__((address_space(3))) u32*)(B + dsts[j]),
                16, 0, 0);
        }
    };

    // fragment LDS byte offsets (kt-invariant); slot = (h*2+b) ^ ((row>>1)&3)
    const int swz = (l31 >> 1) & 3;
    const int s0 = ((h * 2 + 0) ^ swz) * 16;
    const int s1 = ((h * 2 + 1) ^ swz) * 16;
    int aOff0[2], aOff1[2], bOff0[2], bOff1[2];
    #pragma unroll
    for (int mi = 0; mi < 2; ++mi) {
        int rc = wcode * 64 + mi * 32 + l31;
        aOff0[mi] = 8192 + rc * 64 + s0;
        aOff1[mi] = 8192 + rc * 64 + s1;
    }
    #pragma unroll
    for (int ni = 0; ni < 2; ++ni) {
        int rx = wrow * 64 + ni * 32 + l31;
        bOff0[ni] = rx * 64 + s0;
        bOff1[ni] = rx * 64 + s1;
    }

    f32x16 acc[2][2] = {};

    stage(0);
    stage(1);

    #pragma unroll
    for (int kt = 0; kt < KTILES; ++kt) {
        if (kt + 1 < KTILES) {
            asm volatile("s_waitcnt vmcnt(4)" ::: "memory");   // stage(kt) complete
        } else {
            asm volatile("s_waitcnt vmcnt(0)" ::: "memory");
        }
        asm volatile("s_barrier" ::: "memory");
        if (kt + 2 < KTILES) stage(kt + 2);

        const u8* L = &lds[kt % 3][0];
        i32x8 Af[2], Bf[2];
        #pragma unroll
        for (int mi = 0; mi < 2; ++mi) {
            *(i32x4*)&Af[mi]       = *(const i32x4*)(L + aOff0[mi]);
            *((i32x4*)&Af[mi] + 1) = *(const i32x4*)(L + aOff1[mi]);
        }
        #pragma unroll
        for (int ni = 0; ni < 2; ++ni) {
            *(i32x4*)&Bf[ni]       = *(const i32x4*)(L + bOff0[ni]);
            *((i32x4*)&Bf[ni] + 1) = *(const i32x4*)(L + bOff1[ni]);
        }
        __builtin_amdgcn_s_setprio(1);
        #pragma unroll
        for (int ni = 0; ni < 2; ++ni)
            #pragma unroll
            for (int mi = 0; mi < 2; ++mi)
                acc[mi][ni] = __builtin_amdgcn_mfma_scale_f32_32x32x64_f8f6f4(
                    Af[mi], Bf[ni], acc[mi][ni], 0, 0, 0, 127, 0, 127);
        __builtin_amdgcn_s_setprio(0);
    }

    // ---- fold: pack idx into low 13 mantissa bits; float top-3; 1 shfl merge ----
    __syncthreads();
    u64* t3buf = (u64*)&lds[0][0];   // [128 rows][2 wcode][3 slots] = 6KB

    #pragma unroll
    for (int ni = 0; ni < 2; ++ni) {
        float p0 = -3.4e38f, p1 = -3.4e38f, p2 = -3.4e38f;
        #pragma unroll
        for (int mi = 0; mi < 2; ++mi) {
            const u32 cb0u = (u32)(chunkBase + wcode * 64 + mi * 32 + 4 * h);
            #pragma unroll
            for (int reg = 0; reg < 16; ++reg) {
                u32 pr = (__float_as_uint(acc[mi][ni][reg]) & 0xFFFFE000u)
                       | cb0u | (u32)((reg & 3) + 8 * (reg >> 2));
                f3_insert(p0, p1, p2, __uint_as_float(pr));
            }
        }
        // merge with lane^32 (same xrow, complementary codes)
        float q0 = __shfl_xor(p0, 32), q1 = __shfl_xor(p1, 32), q2 = __shfl_xor(p2, 32);
        f3_insert(p0, p1, p2, q0);
        f3_insert(p0, p1, p2, q1);
        f3_insert(p0, p1, p2, q2);
        if (h == 0) {
            int xrl = wrow * 64 + ni * 32 + l31;
            u32 s0b = __float_as_uint(p0);
            u32 k0 = (p0 < 0.0f) ? s0b : (~s0b & 0x7FFFFFFFu);
            u32 s1b = __float_as_uint(p1);
            u32 k1 = (p1 < 0.0f) ? s1b : (~s1b & 0x7FFFFFFFu);
            u32 s2b = __float_as_uint(p2);
            u32 k2 = (p2 < 0.0f) ? s2b : (~s2b & 0x7FFFFFFFu);
            t3buf[(xrl * 2 + wcode) * 3 + 0] = ((u64)k0 << 13) | (u64)(s0b & 8191u);
            t3buf[(xrl * 2 + wcode) * 3 + 1] = ((u64)k1 << 13) | (u64)(s1b & 8191u);
            t3buf[(xrl * 2 + wcode) * 3 + 2] = ((u64)k2 << 13) | (u64)(s2b & 8191u);
        }
    }
    __syncthreads();
    if (t < BMR) {
        u64 best[3];
        best[0] = t3buf[(t * 2 + 0) * 3 + 0];
        best[1] = t3buf[(t * 2 + 0) * 3 + 1];
        best[2] = t3buf[(t * 2 + 0) * 3 + 2];
        t3_insert(best, t3buf[(t * 2 + 1) * 3 + 0]);
        t3_insert(best, t3buf[(t * 2 + 1) * 3 + 1]);
        t3_insert(best, t3buf[(t * 2 + 1) * 3 + 2]);
        size_t o = ((size_t)blockIdx.y * N_ROWS + rowBase + t) * 3;
        top3out[o + 0] = best[0];
        top3out[o + 1] = best[1];
        top3out[o + 2] = best[2];
    }
}

// ---------------- Kernel R: global top-8 of 64x3 keys -> exact np re-decision (r14) ---
__global__ void vq_refine_kernel(const float* __restrict__ x, const float* __restrict__ cb,
                                 const float* __restrict__ Arow, const float* __restrict__ Bcode,
                                 const u64* __restrict__ top3, int* __restrict__ idxOut,
                                 float* __restrict__ out4) {
    int gw = (blockIdx.x * blockDim.x + threadIdx.x) >> 6;
    int lane = threadIdx.x & 63;
    if (gw >= N_ROWS) return;

    const u64* tp = top3 + ((size_t)lane * N_ROWS + gw) * 3;
    u64 a0 = tp[0], a1 = tp[1], a2 = tp[2];

    u64 cand[8];
    #pragma unroll
    for (int j = 0; j < 8; ++j) {
        u64 m = a0;
        #pragma unroll
        for (int s = 1; s < 64; s <<= 1) { u64 o = __shfl_xor(m, s); m = o < m ? o : m; }
        cand[j] = m;
        if (a0 == m) { a0 = a1; a1 = a2; a2 = ~0ull; }
    }

    float Ai = Arow[gw];
    const float* xr = x + (size_t)gw * DIM;
    float xv[8];
    #pragma unroll
    for (int e = 0; e < 8; ++e) xv[e] = xr[e * 64 + lane];

    u64 best = ~0ull;
    #pragma unroll
    for (int j = 0; j < 8; ++j) {
        int c = (int)(cand[j] & 8191u);
        const float* er = cb + (size_t)c * DIM;
        double d = 0.0;
        #pragma unroll
        for (int e = 0; e < 8; ++e)
            d = fma((double)xv[e], (double)er[e * 64 + lane], d);
        #pragma unroll
        for (int m = 1; m < 64; m <<= 1) d += __shfl_xor(d, m);
        float m32 = (float)d;
        float dist = __fsub_rn(__fadd_rn(Ai, Bcode[c]), 2.0f * m32);
        u64 ek = ((u64)__float_as_uint(dist) << 13) | (u64)(u32)c;
        best = ek < best ? ek : best;
    }
    if (lane == 0) {
        int c = (int)(best & 8191u);
        idxOut[gw] = c;
        out4[gw] = (float)c;
    }
}

// ---------------- Kernel C: gather + outputs + per-row loss partial ----------------
__global__ void vq_gather_kernel(const float* __restrict__ x,
                                 const float* __restrict__ cb,
                                 const int* __restrict__ idxArr,
                                 float* __restrict__ out0,
                                 float* __restrict__ out3,
                                 float* __restrict__ rowPart) {
    int gw = (blockIdx.x * blockDim.x + threadIdx.x) >> 6;
    int lane = threadIdx.x & 63;
    if (gw >= N_ROWS) return;
    int idx = idxArr[gw];
    const float2* xp = (const float2*)(x  + (size_t)gw * DIM);
    const float2* qp = (const float2*)(cb + (size_t)idx * DIM);
    float2* o0 = (float2*)(out0 + (size_t)gw * DIM);
    float2* o3 = (float2*)(out3 + (size_t)gw * DIM);
    float part = 0.0f;
    #pragma unroll
    for (int r = 0; r < 4; ++r) {
        int e = r * 64 + lane;
        float2 xv = xp[e];
        float2 qv = qp[e];
        float dx = qv.x - xv.x, dy = qv.y - xv.y;
        part += dx * dx + dy * dy;
        float2 o; o.x = xv.x + dx; o.y = xv.y + dy;
        o0[e] = o;
        o3[e] = qv;
    }
    #pragma unroll
    for (int m = 32; m; m >>= 1) part += __shfl_xor(part, m);
    if (lane == 0) rowPart[gw] = part;
}

// ---------------- Kernel D: deterministic loss reduce ----------------
__global__ void vq_loss_kernel(const float* __restrict__ rowPart,
                               float* __restrict__ out1, float* __restrict__ out2) {
    __shared__ float red[256];
    int t = threadIdx.x;
    float s = 0.0f;
    for (int r = t; r < N_ROWS; r += 256) s += rowPart[r];
    red[t] = s;
    __syncthreads();
    #pragma unroll
    for (int m = 128; m; m >>= 1) {
        if (t < m) red[t] += red[t + m];
        __syncthreads();
    }
    if (t == 0) {
        float loss = red[0] / (float)(N_ROWS * DIM);
        out1[0] = loss;
        out2[0] = loss;
    }
}

extern "C" void kernel_launch(void* const* d_in, const int* in_sizes, int n_in,
                              void* d_out, int out_size, void* d_ws, size_t ws_size,
                              hipStream_t stream) {
    const float* x  = (const float*)d_in[0];   // [16384, 512]
    const float* cb = (const float*)d_in[1];   // [8192, 512]
    float* out  = (float*)d_out;
    float* out0 = out;                         // quantized_out [8388608]
    float* out1 = out + 8388608;               // q_latent_loss [1]
    float* out2 = out + 8388609;               // e_latent_loss [1]
    float* out3 = out + 8388610;               // quantized [8388608]
    float* out4 = out + 16777218;              // idx as float [16384]

    // d_out scratch (stream-ordered; consumed before gather overwrites):
    // xf8 8.4MB + cf8 4.2MB in out0 region; top3 (64*16384*3 u64 = 25MB) in out3 region.
    u32* xf8   = (u32*)out0;                   // [0, 2097152) floats
    u32* cf8   = (u32*)(out + 2097152);        // [2097152, 3145728)
    u64* wsTop3 = (u64*)(out + 8388612);       // [8388612, 14680068)  8B-aligned

    char* ws = (char*)d_ws;
    float* wsA    = (float*)ws;                // 16384 f
    float* wsB    = (float*)(ws + 65536);      // 8192 f
    int*   wsIdx  = (int*)(ws + 98304);        // 16384 int
    float* wsPart = (float*)(ws + 163840);     // 16384 f

    hipLaunchKernelGGL(vq_prep_kernel,   dim3(3072), dim3(256), 0, stream,
                       x, cb, xf8, cf8, wsA, wsB);
    hipLaunchKernelGGL(vq_screen_kernel, dim3(N_ROWS / BMR, CHUNKS), dim3(256), 0, stream,
                       (const u8*)xf8, (const u8*)cf8, wsTop3);
    hipLaunchKernelGGL(vq_refine_kernel, dim3(4096), dim3(256), 0, stream,
                       x, cb, wsA, wsB, wsTop3, wsIdx, out4);
    hipLaunchKernelGGL(vq_gather_kernel, dim3(4096), dim3(256), 0, stream,
                       x, cb, wsIdx, out0, out3, wsPart);
    hipLaunchKernelGGL(vq_loss_kernel,   dim3(1),    dim3(256), 0, stream,
                       wsPart, out1, out2);
}